// Round 14
// baseline (47.439 us; speedup 1.0000x reference)
//
#include <hip/hip_runtime.h>
#include <hip/hip_bf16.h>

#define N_F_IN 128
#define N_F_OUT 32

#define BSHIFT 7
#define BNODES 128             // nodes per bucket
#define BCAP 2560              // per-bucket record capacity (mean 2046, +11 sigma)
#define SCAT_EDGES 8192        // edges per scatter chunk (196 chunks)
#define NBL 1024               // padded bucket-array length
#define OFFT_LD 200            // padded chunk dim of offT (nch = 196)

typedef __attribute__((ext_vector_type(8))) short short8v;
typedef __attribute__((ext_vector_type(4))) float float4v;

static __device__ __forceinline__ unsigned bf16pair(float a, float b) {
    unsigned ua = __float_as_uint(a), ub = __float_as_uint(b);
    ua = (ua + 0x7FFFu + ((ua >> 16) & 1u)) >> 16;
    ub = (ub + 0x7FFFu + ((ub >> 16) & 1u)) >> 16;
    return ua | (ub << 16);
}
static __device__ __forceinline__ unsigned short bf16r(float a) {
    unsigned ua = __float_as_uint(a);
    return (unsigned short)((ua + 0x7FFFu + ((ua >> 16) & 1u)) >> 16);
}

// union: 36.1 KB (scatter blocks use sc; GEMM blocks use wT) -> 4 blocks/CU
union SharedU {
    unsigned short wT[32 * 136];   // transposed bf16 w: wT[col][k], stride 136 (8.5 KB)
    struct {
        int P[NBL];                // histogram, then place cursors (merged A/B)
        int wsum[8];               // per-wave scan partials
        int lrec[SCAT_EDGES];      // bucket-grouped records (32 KB)
    } sc;
};

// ---- phase A (r13-verbatim): blocks [0,nsc) = pure scatter; rest = pure GEMM ----
__global__ __launch_bounds__(512, 8) void phaseA_kernel(const float* __restrict__ x,
                                                        const float* __restrict__ w,
                                                        unsigned short* __restrict__ hb,
                                                        int n,
                                                        const int* __restrict__ src,
                                                        const int* __restrict__ dst,
                                                        int* __restrict__ recs,
                                                        unsigned short* __restrict__ offT,
                                                        int E, int nsc) {
    __shared__ SharedU u;
    const int t = threadIdx.x;
    const int lane = t & 63;
    const int wvid = t >> 6;

    if ((int)blockIdx.x < nsc) {
        // ================= scatter block: group one chunk's edges by bucket ======
        const int chunk = blockIdx.x;
        const int e0 = chunk * SCAT_EDGES;
        const int cnt = min(SCAT_EDGES, E - e0);

        // single global read of this chunk's edges (16/thread, all independent)
        int dv[16], sv[16];
        #pragma unroll
        for (int j = 0; j < 16; ++j) {
            int i = t + j * 512;
            dv[j] = -1; sv[j] = 0;
            if (i < cnt) { dv[j] = dst[e0 + i]; sv[j] = src[e0 + i]; }
        }

        for (int i = t; i < NBL; i += 512) u.sc.P[i] = 0;
        __syncthreads();

        // histogram from registers
        #pragma unroll
        for (int j = 0; j < 16; ++j)
            if (dv[j] >= 0) atomicAdd(&u.sc.P[dv[j] >> BSHIFT], 1);
        __syncthreads();

        // 2 buckets/thread + wave shuffle-scan + cross-wave combine;
        // P is then overwritten in-place with the place cursors
        const int b0 = t * 2;
        const int c0 = u.sc.P[b0], c1 = u.sc.P[b0 + 1];
        const int tot = c0 + c1;
        int sc = tot;
        #pragma unroll
        for (int off = 1; off < 64; off <<= 1) {
            int v = __shfl_up(sc, off, 64);
            if (lane >= off) sc += v;
        }
        if (lane == 63) u.sc.wsum[wvid] = sc;
        __syncthreads();
        int wbase = 0;
        #pragma unroll
        for (int ww = 0; ww < 7; ++ww) wbase += (ww < wvid) ? u.sc.wsum[ww] : 0;
        const int base = wbase + sc - tot;   // exclusive prefix of bucket b0
        u.sc.P[b0] = base;
        u.sc.P[b0 + 1] = base + c0;
        // publish starts (transposed): row = bucket, col = chunk (base <= 8192 fits ushort)
        offT[(long)b0 * OFFT_LD + chunk]       = (unsigned short)base;
        offT[(long)(b0 + 1) * OFFT_LD + chunk] = (unsigned short)(base + c0);
        __syncthreads();

        // place from registers: group records in LDS by bucket
        #pragma unroll
        for (int j = 0; j < 16; ++j) {
            if (dv[j] >= 0) {
                int r = atomicAdd(&u.sc.P[dv[j] >> BSHIFT], 1);
                u.sc.lrec[r] = ((dv[j] & (BNODES - 1)) << 17) | sv[j];
            }
        }
        __syncthreads();

        // write-out: coalesced chunk-major stream, int4
        {
            int* rp = recs + (long)chunk * SCAT_EDGES;
            const int4* lr4 = (const int4*)u.sc.lrec;
            int4* rp4 = (int4*)rp;
            const int c4 = cnt >> 2;
            for (int i = t; i < c4; i += 512) rp4[i] = lr4[i];
            for (int i = (c4 << 2) + t; i < cnt; i += 512) rp[i] = u.sc.lrec[i];
        }
        return;   // scatter block done — frees CU slot
    }

    // ================= GEMM block: 8 waves x 1 m-tile =================
    const int lr = lane & 15;     // A row / B,D col within tile
    const int lg = lane >> 4;     // k-chunk group (8 k each)
    const int ntiles = (n + 15) >> 4;
    const int mtile = ((int)blockIdx.x - nsc) * 8 + wvid;

    // issue x-loads BEFORE w staging: HBM latency hides under stage+barrier
    long rr = (long)mtile * 16 + lr; if (rr >= n) rr = n - 1;
    const float4* q = (const float4*)(x + rr * N_F_IN) + lg * 2;
    float4 p0 = q[0], p1 = q[1], p2 = q[8], p3 = q[9];

    {
        const float4* w4 = (const float4*)w;
        const float4 wa = w4[t * 2], wb = w4[t * 2 + 1];
        int idx = t * 8;
        u.wT[((idx + 0) & 31) * 136 + ((idx + 0) >> 5)] = bf16r(wa.x);
        u.wT[((idx + 1) & 31) * 136 + ((idx + 1) >> 5)] = bf16r(wa.y);
        u.wT[((idx + 2) & 31) * 136 + ((idx + 2) >> 5)] = bf16r(wa.z);
        u.wT[((idx + 3) & 31) * 136 + ((idx + 3) >> 5)] = bf16r(wa.w);
        u.wT[((idx + 4) & 31) * 136 + ((idx + 4) >> 5)] = bf16r(wb.x);
        u.wT[((idx + 5) & 31) * 136 + ((idx + 5) >> 5)] = bf16r(wb.y);
        u.wT[((idx + 6) & 31) * 136 + ((idx + 6) >> 5)] = bf16r(wb.z);
        u.wT[((idx + 7) & 31) * 136 + ((idx + 7) >> 5)] = bf16r(wb.w);
    }
    __syncthreads();

    if (mtile < ntiles) {
        const long R0 = (long)mtile * 16;
        const unsigned short* wr0 = &u.wT[lr * 136];
        const unsigned short* wr1 = &u.wT[(16 + lr) * 136];

        float4v acc0 = {0.f, 0.f, 0.f, 0.f}, acc1 = {0.f, 0.f, 0.f, 0.f};
        #pragma unroll
        for (int ks = 0; ks < 4; ++ks) {
            float4 lo, hi;
            if (ks & 1) { lo = p2; hi = p3; } else { lo = p0; hi = p1; }
            union { short8v v; unsigned uu[4]; } af;
            af.uu[0] = bf16pair(lo.x, lo.y);
            af.uu[1] = bf16pair(lo.z, lo.w);
            af.uu[2] = bf16pair(hi.x, hi.y);
            af.uu[3] = bf16pair(hi.z, hi.w);
            if (ks == 0) { p0 = q[16]; p1 = q[17]; }   // prefetch ks=2
            if (ks == 1) { p2 = q[24]; p3 = q[25]; }   // prefetch ks=3
            short8v bf0 = *(const short8v*)(wr0 + ks * 32 + lg * 8);
            short8v bf1 = *(const short8v*)(wr1 + ks * 32 + lg * 8);
            acc0 = __builtin_amdgcn_mfma_f32_16x16x32_bf16(af.v, bf0, acc0, 0, 0, 0);
            acc1 = __builtin_amdgcn_mfma_f32_16x16x32_bf16(af.v, bf1, acc1, 0, 0, 0);
        }
        #pragma unroll
        for (int reg = 0; reg < 4; ++reg) {
            long row = R0 + lg * 4 + reg;
            if (row < n) {
                hb[row * N_F_OUT + lr]      = bf16r(acc0[reg]);
                hb[row * N_F_OUT + 16 + lr] = bf16r(acc1[reg]);
            }
        }
    }
}

// ---- aggregate: one block (512 thr) per 128-node bucket ----
// Compact via binary search (count fused), LDS sort, DEGREE-BALANCED 8-deep pull.
__global__ __launch_bounds__(512) void agg_kernel(const unsigned short* __restrict__ hb,
                                                  const unsigned short* __restrict__ offT,
                                                  const int* __restrict__ recs,
                                                  float* __restrict__ out, int n, int nch) {
    __shared__ unsigned short s_st[OFFT_LD];                  // run starts (0.4 KB)
    __shared__ int dof[256];                                  // dense offsets per chunk
    __shared__ int srt0[BCAP];                                // compacted raw records
    __shared__ int srt[BCAP];                                 // node-sorted src ids
    __shared__ int cN[BNODES], loff[BNODES + 1], lc[BNODES], wsum8[8];
    __shared__ unsigned char perm[BNODES];                    // degree-rank -> node
    __shared__ int s_tot;
    const int t = threadIdx.x;
    const int b = blockIdx.x;
    const int lane = t & 63;
    const int wv = t >> 6;

    for (int i = t; i < nch; i += 512) s_st[i] = offT[(long)b * OFFT_LD + i];
    int en_t = (t < nch) ? (int)offT[(long)(b + 1) * OFFT_LD + t] : 0;
    if (t < BNODES) cN[t] = 0;
    __syncthreads();

    // per-chunk counts -> exclusive scan -> dense offsets (1 chunk/thread, t < 256)
    if (t < 256) {
        const int cc = (t < nch) ? (en_t - (int)s_st[t]) : 0;
        int sc = cc;
        #pragma unroll
        for (int off = 1; off < 64; off <<= 1) {
            int v = __shfl_up(sc, off, 64);
            if (lane >= off) sc += v;
        }
        if (lane == 63) wsum8[wv] = sc;
        __syncthreads();
        int wbase = 0;
        #pragma unroll
        for (int ww = 0; ww < 3; ++ww) wbase += (ww < wv) ? wsum8[ww] : 0;
        dof[t] = wbase + sc - cc;   // exclusive prefix
        if (t == 255) s_tot = wbase + sc;
    } else {
        __syncthreads();
    }
    __syncthreads();
    const int cnt = min(s_tot, BCAP);

    // compact + fused histogram: each output slot binary-searches its chunk (8 LDS probes)
    for (int i = t; i < cnt; i += 512) {
        int lo = 0, hi = nch;
        while (hi - lo > 1) {
            int mid = (lo + hi) >> 1;
            if (dof[mid] <= i) lo = mid; else hi = mid;
        }
        int v = recs[(long)lo * SCAT_EDGES + (int)s_st[lo] + (i - dof[lo])];
        srt0[i] = v;
        atomicAdd(&cN[(v >> 17) & (BNODES - 1)], 1);
    }
    __syncthreads();

    // exclusive scan over 128 nodes: wave 0, 2 nodes/lane, shuffle scan
    if (t < 64) {
        int v0 = cN[2 * t], v1 = cN[2 * t + 1];
        int s = v0 + v1;
        #pragma unroll
        for (int off = 1; off < 64; off <<= 1) {
            int v = __shfl_up(s, off, 64);
            if (t >= off) s += v;
        }
        int ex = s - v0 - v1;
        loff[2 * t] = ex;
        loff[2 * t + 1] = ex + v0;
        lc[2 * t] = ex;
        lc[2 * t + 1] = ex + v0;
        if (t == 63) loff[BNODES] = s;
    }
    __syncthreads();

    // degree-balanced permutation: rank nodes by degree desc (cN reused as degree)
    if (t < BNODES) cN[t] = loff[t + 1] - loff[t];
    __syncthreads();
    if (t < BNODES) {
        const int d = cN[t];
        int r = 0;
        for (int j = 0; j < BNODES; ++j) {
            int dj = cN[j];
            r += (dj > d) || (dj == d && j < t);
        }
        perm[r] = (unsigned char)t;
    }
    // (no barrier needed yet: perm is read only after the place-pass barrier below)

    // place pass: group src ids by node (x4 MLP)
    int i = t;
    for (; i + 1536 < cnt; i += 2048) {
        int r0 = srt0[i],        r1 = srt0[i + 512];
        int r2 = srt0[i + 1024], r3 = srt0[i + 1536];
        int k0 = atomicAdd(&lc[(r0 >> 17) & (BNODES - 1)], 1); srt[k0] = r0 & 0x1FFFF;
        int k1 = atomicAdd(&lc[(r1 >> 17) & (BNODES - 1)], 1); srt[k1] = r1 & 0x1FFFF;
        int k2 = atomicAdd(&lc[(r2 >> 17) & (BNODES - 1)], 1); srt[k2] = r2 & 0x1FFFF;
        int k3 = atomicAdd(&lc[(r3 >> 17) & (BNODES - 1)], 1); srt[k3] = r3 & 0x1FFFF;
    }
    for (; i < cnt; i += 512) {
        int r0 = srt0[i];
        int k0 = atomicAdd(&lc[(r0 >> 17) & (BNODES - 1)], 1); srt[k0] = r0 & 0x1FFFF;
    }
    __syncthreads();

    // pull: 8 lanes per node, 64 nodes per pass, 8 rows in flight.
    // pass 0 = degree-ranks 0..63 (heavy), pass 1 = ranks 127..64 (light) —
    // intra-wave degrees similar (low divergence), per-group totals balanced.
    const uint2* hq = (const uint2*)hb;   // 8 uint2 per 32-bf16 row
    #pragma unroll
    for (int pp = 0; pp < 2; ++pp) {
        int rank = pp ? (127 - (t >> 3)) : (t >> 3);
        int nl = perm[rank];
        int jj = t & 7;
        int beg = loff[nl], end = loff[nl + 1];
        float4 a0 = make_float4(0.f, 0.f, 0.f, 0.f);
        float4 a1 = a0;
        int k = beg;
        for (; k + 8 <= end; k += 8) {
            uint2 v0 = hq[(size_t)srt[k] * 8 + jj];
            uint2 v1 = hq[(size_t)srt[k + 1] * 8 + jj];
            uint2 v2 = hq[(size_t)srt[k + 2] * 8 + jj];
            uint2 v3 = hq[(size_t)srt[k + 3] * 8 + jj];
            uint2 v4 = hq[(size_t)srt[k + 4] * 8 + jj];
            uint2 v5 = hq[(size_t)srt[k + 5] * 8 + jj];
            uint2 v6 = hq[(size_t)srt[k + 6] * 8 + jj];
            uint2 v7 = hq[(size_t)srt[k + 7] * 8 + jj];
            a0.x += __uint_as_float(v0.x << 16); a0.y += __uint_as_float(v0.x & 0xFFFF0000u);
            a0.z += __uint_as_float(v0.y << 16); a0.w += __uint_as_float(v0.y & 0xFFFF0000u);
            a1.x += __uint_as_float(v1.x << 16); a1.y += __uint_as_float(v1.x & 0xFFFF0000u);
            a1.z += __uint_as_float(v1.y << 16); a1.w += __uint_as_float(v1.y & 0xFFFF0000u);
            a0.x += __uint_as_float(v2.x << 16); a0.y += __uint_as_float(v2.x & 0xFFFF0000u);
            a0.z += __uint_as_float(v2.y << 16); a0.w += __uint_as_float(v2.y & 0xFFFF0000u);
            a1.x += __uint_as_float(v3.x << 16); a1.y += __uint_as_float(v3.x & 0xFFFF0000u);
            a1.z += __uint_as_float(v3.y << 16); a1.w += __uint_as_float(v3.y & 0xFFFF0000u);
            a0.x += __uint_as_float(v4.x << 16); a0.y += __uint_as_float(v4.x & 0xFFFF0000u);
            a0.z += __uint_as_float(v4.y << 16); a0.w += __uint_as_float(v4.y & 0xFFFF0000u);
            a1.x += __uint_as_float(v5.x << 16); a1.y += __uint_as_float(v5.x & 0xFFFF0000u);
            a1.z += __uint_as_float(v5.y << 16); a1.w += __uint_as_float(v5.y & 0xFFFF0000u);
            a0.x += __uint_as_float(v6.x << 16); a0.y += __uint_as_float(v6.x & 0xFFFF0000u);
            a0.z += __uint_as_float(v6.y << 16); a0.w += __uint_as_float(v6.y & 0xFFFF0000u);
            a1.x += __uint_as_float(v7.x << 16); a1.y += __uint_as_float(v7.x & 0xFFFF0000u);
            a1.z += __uint_as_float(v7.y << 16); a1.w += __uint_as_float(v7.y & 0xFFFF0000u);
        }
        for (; k + 4 <= end; k += 4) {
            uint2 v0 = hq[(size_t)srt[k] * 8 + jj];
            uint2 v1 = hq[(size_t)srt[k + 1] * 8 + jj];
            uint2 v2 = hq[(size_t)srt[k + 2] * 8 + jj];
            uint2 v3 = hq[(size_t)srt[k + 3] * 8 + jj];
            a0.x += __uint_as_float(v0.x << 16); a0.y += __uint_as_float(v0.x & 0xFFFF0000u);
            a0.z += __uint_as_float(v0.y << 16); a0.w += __uint_as_float(v0.y & 0xFFFF0000u);
            a1.x += __uint_as_float(v1.x << 16); a1.y += __uint_as_float(v1.x & 0xFFFF0000u);
            a1.z += __uint_as_float(v1.y << 16); a1.w += __uint_as_float(v1.y & 0xFFFF0000u);
            a0.x += __uint_as_float(v2.x << 16); a0.y += __uint_as_float(v2.x & 0xFFFF0000u);
            a0.z += __uint_as_float(v2.y << 16); a0.w += __uint_as_float(v2.y & 0xFFFF0000u);
            a1.x += __uint_as_float(v3.x << 16); a1.y += __uint_as_float(v3.x & 0xFFFF0000u);
            a1.z += __uint_as_float(v3.y << 16); a1.w += __uint_as_float(v3.y & 0xFFFF0000u);
        }
        for (; k < end; ++k) {
            uint2 v0 = hq[(size_t)srt[k] * 8 + jj];
            a0.x += __uint_as_float(v0.x << 16); a0.y += __uint_as_float(v0.x & 0xFFFF0000u);
            a0.z += __uint_as_float(v0.y << 16); a0.w += __uint_as_float(v0.y & 0xFFFF0000u);
        }
        float4 a = make_float4(a0.x + a1.x, a0.y + a1.y, a0.z + a1.z, a0.w + a1.w);
        long node = (long)b * BNODES + nl;
        if (node < n) *(float4*)&out[node * N_F_OUT + jj * 4] = a;
    }
}

extern "C" void kernel_launch(void* const* d_in, const int* in_sizes, int n_in,
                              void* d_out, int out_size, void* d_ws, size_t ws_size,
                              hipStream_t stream) {
    const float* x = (const float*)d_in[0];
    const float* w = (const float*)d_in[1];
    const int* src = (const int*)d_in[2];
    const int* dst = (const int*)d_in[3];
    float* out = (float*)d_out;

    const int n = in_sizes[0] / N_F_IN;   // 100000
    const int E = in_sizes[2];            // 1600000
    const int NB = (n + BNODES - 1) >> BSHIFT;           // 782
    const int nch = (E + SCAT_EDGES - 1) / SCAT_EDGES;   // 196

    char* p = (char*)d_ws;
    unsigned short* hb = (unsigned short*)p;
    p += (((size_t)n * N_F_OUT * sizeof(unsigned short)) + 255) & ~(size_t)255;
    int* recs = (int*)p;
    p += (((size_t)nch * SCAT_EDGES * sizeof(int)) + 255) & ~(size_t)255;   // 6.4 MB
    unsigned short* offT = (unsigned short*)p;
    p += (((size_t)1025 * OFFT_LD * sizeof(unsigned short)) + 255) & ~(size_t)255;  // 410 KB

    const int ntiles = (n + 15) >> 4;                    // 6250
    const int ngemm = (ntiles + 7) >> 3;                 // 782 (8 tiles each)
    const int nblk = nch + ngemm;                        // 978 <= 1024: all resident

    phaseA_kernel<<<nblk, 512, 0, stream>>>(x, w, hb, n, src, dst, recs, offT, E, nch);
    agg_kernel<<<NB, 512, 0, stream>>>(hb, offT, recs, out, n, nch);
}

// Round 15
// 46.219 us; speedup vs baseline: 1.0264x; 1.0264x over previous
//
#include <hip/hip_runtime.h>
#include <hip/hip_bf16.h>

#define N_F_IN 128
#define N_F_OUT 32

#define BSHIFT 7
#define BNODES 128             // nodes per bucket
#define BCAP 2560              // per-bucket record capacity (mean 2046, +11 sigma)
#define SCAT_EDGES 8192        // edges per scatter chunk (196 chunks)
#define NBL 1024               // padded bucket-array length
#define OFFT_LD 200            // padded chunk dim of offT (nch = 196)

typedef __attribute__((ext_vector_type(8))) short short8v;
typedef __attribute__((ext_vector_type(4))) float float4v;

static __device__ __forceinline__ unsigned bf16pair(float a, float b) {
    unsigned ua = __float_as_uint(a), ub = __float_as_uint(b);
    ua = (ua + 0x7FFFu + ((ua >> 16) & 1u)) >> 16;
    ub = (ub + 0x7FFFu + ((ub >> 16) & 1u)) >> 16;
    return ua | (ub << 16);
}
static __device__ __forceinline__ unsigned short bf16r(float a) {
    unsigned ua = __float_as_uint(a);
    return (unsigned short)((ua + 0x7FFFu + ((ua >> 16) & 1u)) >> 16);
}

// union: 36.1 KB (scatter blocks use sc; GEMM blocks use wT) -> 4 blocks/CU
union SharedU {
    unsigned short wT[32 * 136];   // transposed bf16 w: wT[col][k], stride 136 (8.5 KB)
    struct {
        int P[NBL];                // histogram, then place cursors (merged A/B)
        int wsum[8];               // per-wave scan partials
        int lrec[SCAT_EDGES];      // bucket-grouped records (32 KB)
    } sc;
};

// ---- phase A: blocks [0,nsc) = pure scatter (one 8192-edge chunk each);
// ----          blocks [nsc, nsc+ngemm) = pure GEMM (8 m-tiles, 1 per wave).
// ---- 196 + 782 = 978 blocks <= 1024 co-residency: all resident, fine packing.
__global__ __launch_bounds__(512, 8) void phaseA_kernel(const float* __restrict__ x,
                                                        const float* __restrict__ w,
                                                        unsigned short* __restrict__ hb,
                                                        int n,
                                                        const int* __restrict__ src,
                                                        const int* __restrict__ dst,
                                                        int* __restrict__ recs,
                                                        unsigned short* __restrict__ offT,
                                                        int E, int nsc) {
    __shared__ SharedU u;
    const int t = threadIdx.x;
    const int lane = t & 63;
    const int wvid = t >> 6;

    if ((int)blockIdx.x < nsc) {
        // ================= scatter block: group one chunk's edges by bucket ======
        const int chunk = blockIdx.x;
        const int e0 = chunk * SCAT_EDGES;
        const int cnt = min(SCAT_EDGES, E - e0);

        // single global read of this chunk's edges (16/thread, all independent)
        int dv[16], sv[16];
        #pragma unroll
        for (int j = 0; j < 16; ++j) {
            int i = t + j * 512;
            dv[j] = -1; sv[j] = 0;
            if (i < cnt) { dv[j] = dst[e0 + i]; sv[j] = src[e0 + i]; }
        }

        for (int i = t; i < NBL; i += 512) u.sc.P[i] = 0;
        __syncthreads();

        // histogram from registers
        #pragma unroll
        for (int j = 0; j < 16; ++j)
            if (dv[j] >= 0) atomicAdd(&u.sc.P[dv[j] >> BSHIFT], 1);
        __syncthreads();

        // 2 buckets/thread + wave shuffle-scan + cross-wave combine;
        // P is then overwritten in-place with the place cursors
        const int b0 = t * 2;
        const int c0 = u.sc.P[b0], c1 = u.sc.P[b0 + 1];
        const int tot = c0 + c1;
        int sc = tot;
        #pragma unroll
        for (int off = 1; off < 64; off <<= 1) {
            int v = __shfl_up(sc, off, 64);
            if (lane >= off) sc += v;
        }
        if (lane == 63) u.sc.wsum[wvid] = sc;
        __syncthreads();
        int wbase = 0;
        #pragma unroll
        for (int ww = 0; ww < 7; ++ww) wbase += (ww < wvid) ? u.sc.wsum[ww] : 0;
        const int base = wbase + sc - tot;   // exclusive prefix of bucket b0
        u.sc.P[b0] = base;
        u.sc.P[b0 + 1] = base + c0;
        // publish starts (transposed): row = bucket, col = chunk (base <= 8192 fits ushort)
        offT[(long)b0 * OFFT_LD + chunk]       = (unsigned short)base;
        offT[(long)(b0 + 1) * OFFT_LD + chunk] = (unsigned short)(base + c0);
        __syncthreads();

        // place from registers: group records in LDS by bucket
        #pragma unroll
        for (int j = 0; j < 16; ++j) {
            if (dv[j] >= 0) {
                int r = atomicAdd(&u.sc.P[dv[j] >> BSHIFT], 1);
                u.sc.lrec[r] = ((dv[j] & (BNODES - 1)) << 17) | sv[j];
            }
        }
        __syncthreads();

        // write-out: coalesced chunk-major stream, int4
        {
            int* rp = recs + (long)chunk * SCAT_EDGES;
            const int4* lr4 = (const int4*)u.sc.lrec;
            int4* rp4 = (int4*)rp;
            const int c4 = cnt >> 2;
            for (int i = t; i < c4; i += 512) rp4[i] = lr4[i];
            for (int i = (c4 << 2) + t; i < cnt; i += 512) rp[i] = u.sc.lrec[i];
        }
        return;   // scatter block done — frees CU slot
    }

    // ================= GEMM block: 8 waves x 1 m-tile =================
    const int lr = lane & 15;     // A row / B,D col within tile
    const int lg = lane >> 4;     // k-chunk group (8 k each)
    const int ntiles = (n + 15) >> 4;
    const int mtile = ((int)blockIdx.x - nsc) * 8 + wvid;

    // issue x-loads BEFORE w staging: HBM latency hides under stage+barrier
    long rr = (long)mtile * 16 + lr; if (rr >= n) rr = n - 1;
    const float4* q = (const float4*)(x + rr * N_F_IN) + lg * 2;
    float4 p0 = q[0], p1 = q[1], p2 = q[8], p3 = q[9];

    {
        const float4* w4 = (const float4*)w;
        const float4 wa = w4[t * 2], wb = w4[t * 2 + 1];
        int idx = t * 8;
        u.wT[((idx + 0) & 31) * 136 + ((idx + 0) >> 5)] = bf16r(wa.x);
        u.wT[((idx + 1) & 31) * 136 + ((idx + 1) >> 5)] = bf16r(wa.y);
        u.wT[((idx + 2) & 31) * 136 + ((idx + 2) >> 5)] = bf16r(wa.z);
        u.wT[((idx + 3) & 31) * 136 + ((idx + 3) >> 5)] = bf16r(wa.w);
        u.wT[((idx + 4) & 31) * 136 + ((idx + 4) >> 5)] = bf16r(wb.x);
        u.wT[((idx + 5) & 31) * 136 + ((idx + 5) >> 5)] = bf16r(wb.y);
        u.wT[((idx + 6) & 31) * 136 + ((idx + 6) >> 5)] = bf16r(wb.z);
        u.wT[((idx + 7) & 31) * 136 + ((idx + 7) >> 5)] = bf16r(wb.w);
    }
    __syncthreads();

    if (mtile < ntiles) {
        const long R0 = (long)mtile * 16;
        const unsigned short* wr0 = &u.wT[lr * 136];
        const unsigned short* wr1 = &u.wT[(16 + lr) * 136];

        float4v acc0 = {0.f, 0.f, 0.f, 0.f}, acc1 = {0.f, 0.f, 0.f, 0.f};
        #pragma unroll
        for (int ks = 0; ks < 4; ++ks) {
            float4 lo, hi;
            if (ks & 1) { lo = p2; hi = p3; } else { lo = p0; hi = p1; }
            union { short8v v; unsigned uu[4]; } af;
            af.uu[0] = bf16pair(lo.x, lo.y);
            af.uu[1] = bf16pair(lo.z, lo.w);
            af.uu[2] = bf16pair(hi.x, hi.y);
            af.uu[3] = bf16pair(hi.z, hi.w);
            if (ks == 0) { p0 = q[16]; p1 = q[17]; }   // prefetch ks=2
            if (ks == 1) { p2 = q[24]; p3 = q[25]; }   // prefetch ks=3
            short8v bf0 = *(const short8v*)(wr0 + ks * 32 + lg * 8);
            short8v bf1 = *(const short8v*)(wr1 + ks * 32 + lg * 8);
            acc0 = __builtin_amdgcn_mfma_f32_16x16x32_bf16(af.v, bf0, acc0, 0, 0, 0);
            acc1 = __builtin_amdgcn_mfma_f32_16x16x32_bf16(af.v, bf1, acc1, 0, 0, 0);
        }
        #pragma unroll
        for (int reg = 0; reg < 4; ++reg) {
            long row = R0 + lg * 4 + reg;
            if (row < n) {
                hb[row * N_F_OUT + lr]      = bf16r(acc0[reg]);
                hb[row * N_F_OUT + 16 + lr] = bf16r(acc1[reg]);
            }
        }
    }
}

// ---- aggregate (r12-verbatim): one block (512 thr) per 128-node bucket ----
// Compact 196 runs via index-inverted binary search (count fused in), LDS sort, 8-deep pull.
__global__ __launch_bounds__(512) void agg_kernel(const unsigned short* __restrict__ hb,
                                                  const unsigned short* __restrict__ offT,
                                                  const int* __restrict__ recs,
                                                  float* __restrict__ out, int n, int nch) {
    __shared__ unsigned short s_st[OFFT_LD];                  // run starts (0.4 KB)
    __shared__ int dof[256];                                  // dense offsets per chunk
    __shared__ int srt0[BCAP];                                // compacted raw records
    __shared__ int srt[BCAP];                                 // node-sorted src ids
    __shared__ int cN[BNODES], loff[BNODES + 1], lc[BNODES], wsum8[8];
    __shared__ int s_tot;
    const int t = threadIdx.x;
    const int b = blockIdx.x;
    const int lane = t & 63;
    const int wv = t >> 6;

    for (int i = t; i < nch; i += 512) s_st[i] = offT[(long)b * OFFT_LD + i];
    int en_t = (t < nch) ? (int)offT[(long)(b + 1) * OFFT_LD + t] : 0;
    if (t < BNODES) cN[t] = 0;
    __syncthreads();

    // per-chunk counts -> exclusive scan -> dense offsets (1 chunk/thread, t < 256)
    if (t < 256) {
        const int cc = (t < nch) ? (en_t - (int)s_st[t]) : 0;
        int sc = cc;
        #pragma unroll
        for (int off = 1; off < 64; off <<= 1) {
            int v = __shfl_up(sc, off, 64);
            if (lane >= off) sc += v;
        }
        if (lane == 63) wsum8[wv] = sc;
        __syncthreads();
        int wbase = 0;
        #pragma unroll
        for (int ww = 0; ww < 3; ++ww) wbase += (ww < wv) ? wsum8[ww] : 0;
        dof[t] = wbase + sc - cc;   // exclusive prefix
        if (t == 255) s_tot = wbase + sc;
    } else {
        __syncthreads();
    }
    __syncthreads();
    const int cnt = min(s_tot, BCAP);

    // compact + fused histogram: each output slot binary-searches its chunk (8 LDS probes)
    for (int i = t; i < cnt; i += 512) {
        int lo = 0, hi = nch;
        while (hi - lo > 1) {
            int mid = (lo + hi) >> 1;
            if (dof[mid] <= i) lo = mid; else hi = mid;
        }
        int v = recs[(long)lo * SCAT_EDGES + (int)s_st[lo] + (i - dof[lo])];
        srt0[i] = v;
        atomicAdd(&cN[(v >> 17) & (BNODES - 1)], 1);
    }
    __syncthreads();

    // exclusive scan over 128 nodes: wave 0, 2 nodes/lane, shuffle scan
    if (t < 64) {
        int v0 = cN[2 * t], v1 = cN[2 * t + 1];
        int s = v0 + v1;
        #pragma unroll
        for (int off = 1; off < 64; off <<= 1) {
            int v = __shfl_up(s, off, 64);
            if (t >= off) s += v;
        }
        int ex = s - v0 - v1;
        loff[2 * t] = ex;
        loff[2 * t + 1] = ex + v0;
        lc[2 * t] = ex;
        lc[2 * t + 1] = ex + v0;
        if (t == 63) loff[BNODES] = s;
    }
    __syncthreads();

    // place pass: group src ids by node (x4 MLP)
    int i = t;
    for (; i + 1536 < cnt; i += 2048) {
        int r0 = srt0[i],        r1 = srt0[i + 512];
        int r2 = srt0[i + 1024], r3 = srt0[i + 1536];
        int k0 = atomicAdd(&lc[(r0 >> 17) & (BNODES - 1)], 1); srt[k0] = r0 & 0x1FFFF;
        int k1 = atomicAdd(&lc[(r1 >> 17) & (BNODES - 1)], 1); srt[k1] = r1 & 0x1FFFF;
        int k2 = atomicAdd(&lc[(r2 >> 17) & (BNODES - 1)], 1); srt[k2] = r2 & 0x1FFFF;
        int k3 = atomicAdd(&lc[(r3 >> 17) & (BNODES - 1)], 1); srt[k3] = r3 & 0x1FFFF;
    }
    for (; i < cnt; i += 512) {
        int r0 = srt0[i];
        int k0 = atomicAdd(&lc[(r0 >> 17) & (BNODES - 1)], 1); srt[k0] = r0 & 0x1FFFF;
    }
    __syncthreads();

    // pull: 8 lanes per node, 64 nodes per pass, 8 rows in flight
    const uint2* hq = (const uint2*)hb;   // 8 uint2 per 32-bf16 row
    #pragma unroll
    for (int pp = 0; pp < 2; ++pp) {
        int nl = pp * 64 + (t >> 3);
        int jj = t & 7;
        int beg = loff[nl], end = loff[nl + 1];
        float4 a0 = make_float4(0.f, 0.f, 0.f, 0.f);
        float4 a1 = a0;
        int k = beg;
        for (; k + 8 <= end; k += 8) {
            uint2 v0 = hq[(size_t)srt[k] * 8 + jj];
            uint2 v1 = hq[(size_t)srt[k + 1] * 8 + jj];
            uint2 v2 = hq[(size_t)srt[k + 2] * 8 + jj];
            uint2 v3 = hq[(size_t)srt[k + 3] * 8 + jj];
            uint2 v4 = hq[(size_t)srt[k + 4] * 8 + jj];
            uint2 v5 = hq[(size_t)srt[k + 5] * 8 + jj];
            uint2 v6 = hq[(size_t)srt[k + 6] * 8 + jj];
            uint2 v7 = hq[(size_t)srt[k + 7] * 8 + jj];
            a0.x += __uint_as_float(v0.x << 16); a0.y += __uint_as_float(v0.x & 0xFFFF0000u);
            a0.z += __uint_as_float(v0.y << 16); a0.w += __uint_as_float(v0.y & 0xFFFF0000u);
            a1.x += __uint_as_float(v1.x << 16); a1.y += __uint_as_float(v1.x & 0xFFFF0000u);
            a1.z += __uint_as_float(v1.y << 16); a1.w += __uint_as_float(v1.y & 0xFFFF0000u);
            a0.x += __uint_as_float(v2.x << 16); a0.y += __uint_as_float(v2.x & 0xFFFF0000u);
            a0.z += __uint_as_float(v2.y << 16); a0.w += __uint_as_float(v2.y & 0xFFFF0000u);
            a1.x += __uint_as_float(v3.x << 16); a1.y += __uint_as_float(v3.x & 0xFFFF0000u);
            a1.z += __uint_as_float(v3.y << 16); a1.w += __uint_as_float(v3.y & 0xFFFF0000u);
            a0.x += __uint_as_float(v4.x << 16); a0.y += __uint_as_float(v4.x & 0xFFFF0000u);
            a0.z += __uint_as_float(v4.y << 16); a0.w += __uint_as_float(v4.y & 0xFFFF0000u);
            a1.x += __uint_as_float(v5.x << 16); a1.y += __uint_as_float(v5.x & 0xFFFF0000u);
            a1.z += __uint_as_float(v5.y << 16); a1.w += __uint_as_float(v5.y & 0xFFFF0000u);
            a0.x += __uint_as_float(v6.x << 16); a0.y += __uint_as_float(v6.x & 0xFFFF0000u);
            a0.z += __uint_as_float(v6.y << 16); a0.w += __uint_as_float(v6.y & 0xFFFF0000u);
            a1.x += __uint_as_float(v7.x << 16); a1.y += __uint_as_float(v7.x & 0xFFFF0000u);
            a1.z += __uint_as_float(v7.y << 16); a1.w += __uint_as_float(v7.y & 0xFFFF0000u);
        }
        for (; k + 4 <= end; k += 4) {
            uint2 v0 = hq[(size_t)srt[k] * 8 + jj];
            uint2 v1 = hq[(size_t)srt[k + 1] * 8 + jj];
            uint2 v2 = hq[(size_t)srt[k + 2] * 8 + jj];
            uint2 v3 = hq[(size_t)srt[k + 3] * 8 + jj];
            a0.x += __uint_as_float(v0.x << 16); a0.y += __uint_as_float(v0.x & 0xFFFF0000u);
            a0.z += __uint_as_float(v0.y << 16); a0.w += __uint_as_float(v0.y & 0xFFFF0000u);
            a1.x += __uint_as_float(v1.x << 16); a1.y += __uint_as_float(v1.x & 0xFFFF0000u);
            a1.z += __uint_as_float(v1.y << 16); a1.w += __uint_as_float(v1.y & 0xFFFF0000u);
            a0.x += __uint_as_float(v2.x << 16); a0.y += __uint_as_float(v2.x & 0xFFFF0000u);
            a0.z += __uint_as_float(v2.y << 16); a0.w += __uint_as_float(v2.y & 0xFFFF0000u);
            a1.x += __uint_as_float(v3.x << 16); a1.y += __uint_as_float(v3.x & 0xFFFF0000u);
            a1.z += __uint_as_float(v3.y << 16); a1.w += __uint_as_float(v3.y & 0xFFFF0000u);
        }
        for (; k < end; ++k) {
            uint2 v0 = hq[(size_t)srt[k] * 8 + jj];
            a0.x += __uint_as_float(v0.x << 16); a0.y += __uint_as_float(v0.x & 0xFFFF0000u);
            a0.z += __uint_as_float(v0.y << 16); a0.w += __uint_as_float(v0.y & 0xFFFF0000u);
        }
        float4 a = make_float4(a0.x + a1.x, a0.y + a1.y, a0.z + a1.z, a0.w + a1.w);
        long node = (long)b * BNODES + nl;
        if (node < n) *(float4*)&out[node * N_F_OUT + jj * 4] = a;
    }
}

extern "C" void kernel_launch(void* const* d_in, const int* in_sizes, int n_in,
                              void* d_out, int out_size, void* d_ws, size_t ws_size,
                              hipStream_t stream) {
    const float* x = (const float*)d_in[0];
    const float* w = (const float*)d_in[1];
    const int* src = (const int*)d_in[2];
    const int* dst = (const int*)d_in[3];
    float* out = (float*)d_out;

    const int n = in_sizes[0] / N_F_IN;   // 100000
    const int E = in_sizes[2];            // 1600000
    const int NB = (n + BNODES - 1) >> BSHIFT;           // 782
    const int nch = (E + SCAT_EDGES - 1) / SCAT_EDGES;   // 196

    char* p = (char*)d_ws;
    unsigned short* hb = (unsigned short*)p;
    p += (((size_t)n * N_F_OUT * sizeof(unsigned short)) + 255) & ~(size_t)255;
    int* recs = (int*)p;
    p += (((size_t)nch * SCAT_EDGES * sizeof(int)) + 255) & ~(size_t)255;   // 6.4 MB
    unsigned short* offT = (unsigned short*)p;
    p += (((size_t)1025 * OFFT_LD * sizeof(unsigned short)) + 255) & ~(size_t)255;  // 410 KB

    const int ntiles = (n + 15) >> 4;                    // 6250
    const int ngemm = (ntiles + 7) >> 3;                 // 782 (8 tiles each)
    const int nblk = nch + ngemm;                        // 978 <= 1024: all resident

    phaseA_kernel<<<nblk, 512, 0, stream>>>(x, w, hb, n, src, dst, recs, offT, E, nch);
    agg_kernel<<<NB, 512, 0, stream>>>(hb, offT, recs, out, n, nch);
}